// Round 1
// baseline (24.710 us; speedup 1.0000x reference)
//
#include <hip/hip_runtime.h>

// Polyphase resampler, up=2 / down=3, FILT=128 taps, fp32.
//   out[2g]   = 2 * sum_{m=0..63} x[31+3g-m] * f[2m+1]
//   out[2g+1] = 2 * sum_{m=0..63} x[33+3g-m] * f[2m]
// x zero-extended outside [0,N). out_len = ceil(2N/3).

constexpr int R   = 8;            // output pairs per thread
constexpr int BT  = 256;          // threads per block
constexpr int PPB = R * BT;       // pairs per block (2048, multiple of 4 => alignment)
constexpr int WIN = 3 * R + 64;   // 88-float x window per thread (87 used + 1 pad)

__global__ __launch_bounds__(BT) void resample23_kernel(
    const float* __restrict__ x,
    const float* __restrict__ filt,
    float* __restrict__ out,
    int N, int out_size)
{
    __shared__ float fs[128];               // fs[k] = 2*f[k]
    const int t = threadIdx.x;
    if (t < 128) fs[t] = 2.0f * filt[t];
    __syncthreads();

    const int g    = blockIdx.x * PPB + t * R;  // first pair this thread owns
    const int base = 3 * g - 32;                // x index of xr[0]; 16B-aligned (base%4==0)

    // ---- load x window into registers (all indices compile-time) ----
    float xr[WIN];
    const bool fast = (base >= 0) && (base + WIN <= N);
    if (fast) {
        const float4* xv = reinterpret_cast<const float4*>(x + base);
        #pragma unroll
        for (int i = 0; i < WIN / 4; ++i) {
            float4 v = xv[i];
            xr[4*i+0] = v.x; xr[4*i+1] = v.y; xr[4*i+2] = v.z; xr[4*i+3] = v.w;
        }
    } else {
        #pragma unroll
        for (int i = 0; i < WIN; ++i) {
            int idx = base + i;
            xr[i] = (idx >= 0 && idx < N) ? x[idx] : 0.0f;
        }
    }

    // ---- polyphase FIR: 64 taps per phase, 2 phases, R pairs ----
    float acc[2 * R];
    #pragma unroll
    for (int i = 0; i < 2 * R; ++i) acc[i] = 0.0f;

    #pragma unroll
    for (int mm = 0; mm < 32; ++mm) {       // two taps (m0,m1) per iteration
        float4 c = *reinterpret_cast<const float4*>(&fs[4 * mm]);
        // c.x=2f[4mm]  c.y=2f[4mm+1]  c.z=2f[4mm+2]  c.w=2f[4mm+3]
        const int m0 = 2 * mm, m1 = 2 * mm + 1;
        #pragma unroll
        for (int p = 0; p < R; ++p) {
            acc[2*p]     += xr[63 - m0 + 3*p] * c.y;   // even output, f[2m0+1]
            acc[2*p + 1] += xr[65 - m0 + 3*p] * c.x;   // odd  output, f[2m0]
            acc[2*p]     += xr[63 - m1 + 3*p] * c.w;   // even output, f[2m1+1]
            acc[2*p + 1] += xr[65 - m1 + 3*p] * c.z;   // odd  output, f[2m1]
        }
    }

    // ---- store 16 contiguous outputs ----
    const int j0 = 2 * g;
    if (j0 + 2 * R <= out_size) {
        float4* ov = reinterpret_cast<float4*>(out + j0);
        #pragma unroll
        for (int q = 0; q < (2 * R) / 4; ++q)
            ov[q] = make_float4(acc[4*q], acc[4*q+1], acc[4*q+2], acc[4*q+3]);
    } else {
        #pragma unroll
        for (int i = 0; i < 2 * R; ++i)
            if (j0 + i < out_size) out[j0 + i] = acc[i];
    }
}

extern "C" void kernel_launch(void* const* d_in, const int* in_sizes, int n_in,
                              void* d_out, int out_size, void* d_ws, size_t ws_size,
                              hipStream_t stream)
{
    const float* x    = (const float*)d_in[0];
    const float* filt = (const float*)d_in[1];
    float* out        = (float*)d_out;
    const int N       = in_sizes[0];

    const int n_pairs = (out_size + 1) / 2;
    const int blocks  = (n_pairs + PPB - 1) / PPB;
    resample23_kernel<<<blocks, BT, 0, stream>>>(x, filt, out, N, out_size);
}